// Round 7
// baseline (91.973 us; speedup 1.0000x reference)
//
#include <hip/hip_runtime.h>
#include <math.h>

#define PH 7
#define PW 7
#define BB 4
#define HH 64
#define WW 64
#define CC 256
#define RR 128
#define CH4 (CC / 4)                   // 64 float4 per pixel
#define BINS_PER_IMG (RR * PH * PW)    // 6272
#define NBINS (BB * BINS_PER_IMG)      // 25088
#define NBLK 2048                      // 8 blocks/CU exactly (256 CUs)
#define BLK_HALF 256                   // blocks per (xcd&1) half slot
#define WPI 2048                       // waves per image (512 blk * 4)

typedef float f4 __attribute__((ext_vector_type(4)));

__device__ __forceinline__ f4 max4(f4 a, f4 b) {
    f4 r;
    r.x = fmaxf(a.x, b.x); r.y = fmaxf(a.y, b.y);
    r.z = fmaxf(a.z, b.z); r.w = fmaxf(a.w, b.w);
    return r;
}
__device__ __forceinline__ int rfl(int x) { return __builtin_amdgcn_readfirstlane(x); }

// R7: dispatch-floor theory. 2048 workgroups (vs 6272) at exact full
// occupancy (8 blk/CU * 4 waves = 32 waves/CU); each wave handles 3-4 bins
// in an unrolled independent loop — ROI s_loads and pixel-load batches from
// different bins can interleave, and the SPI launches 3x fewer workgroups.
// Per-bin math identical to R4 (verified exact): scalar-pipe offsets via
// readfirstlane, 8-deep load batches, clamp-dup idempotent under max.
// XCD swizzle: image b -> xcds {2b,2b+1} (R2: FETCH 50->12MB). NT stores.
__global__ __launch_bounds__(256, 8) void ROIPoolingLayer_62079457296467_kernel(
    const float* __restrict__ fm, const float* __restrict__ rois,
    float* __restrict__ out)
{
    const int lane = threadIdx.x & 63;
    const int wave = rfl((int)threadIdx.x >> 6);

    // 2048 blocks = 8 xcds x 256; image b = xcd>>1; 512 blocks per image.
    const int bid   = blockIdx.x;
    const int xcd   = bid & 7;
    const int b     = xcd >> 1;
    const int blkin = (xcd & 1) * BLK_HALF + (bid >> 3);  // 0..511 in image
    const int wv    = blkin * 4 + wave;                   // 0..2047 in image

    const f4* __restrict__ fmb  = (const f4*)fm + (size_t)b * (HH * WW) * CH4 + lane;
    const f4* __restrict__ roib = (const f4*)rois + (size_t)b * RR;
    f4* __restrict__ outb = (f4*)out + (size_t)b * BINS_PER_IMG * CH4 + lane;

#pragma unroll
    for (int t = 0; t < 4; ++t) {
        const int local = wv + t * WPI;          // bin id in image
        if (local < BINS_PER_IMG) {              // t=3 only for wv<128
            const int r   = local / (PH * PW);
            const int bin = local - r * (PH * PW);
            const int ph  = bin / PW;
            const int pw  = bin - ph * PW;

            // ROI decode (reference fp32 semantics, truncating casts)
            const f4 roi = roib[r];
            const int h0 = rfl((int)floorf((float)HH * roi.x));
            const int w0 = rfl((int)floorf((float)WW * roi.y));
            const int h1 = rfl((int)floorf((float)HH * roi.z));
            const int w1 = rfl((int)floorf((float)WW * roi.w));
            const int rh = h1 - h0, rw = w1 - w0;
            const int hstep = max(rh / PH, 1), wstep = max(rw / PW, 1);

            int hs = h0 + ph * hstep;
            int he = (ph == PH - 1) ? (h0 + rh) : (hs + hstep);
            he = min(he, h0 + rh);  he = min(he, HH);
            int ws = w0 + pw * wstep;
            int we = (pw == PW - 1) ? (w0 + rw) : (ws + wstep);
            we = min(we, w0 + rw);  we = min(we, WW);

            const int wbin = we - ws;
            const int npix = (he - hs) * wbin;   // typ ~15
            f4 acc = (f4){-INFINITY, -INFINITY, -INFINITY, -INFINITY};

            if (npix > 0) {
                const int sbase = rfl(hs * WW + ws);
                // magic div by wbin: exact for pk*e < 2^16 (pk<=120, e<wbin<=~11)
                const unsigned m = (65536u + (unsigned)wbin - 1) / (unsigned)wbin;
                for (int p = 0; p < npix; p += 8) {
                    f4 v[8];
#pragma unroll
                    for (int k = 0; k < 8; ++k) {
                        const int pk  = min(p + k, npix - 1);       // clamp: dup ok
                        const int q   = (int)(((unsigned)pk * m) >> 16);
                        const int off = rfl(sbase + q * WW + (pk - q * wbin));
                        v[k] = fmb[(size_t)off * CH4];
                    }
#pragma unroll
                    for (int k = 0; k < 4; ++k) v[k] = max4(v[k], v[k + 4]);
                    acc = max4(acc, max4(max4(v[0], v[1]), max4(v[2], v[3])));
                }
            }

            __builtin_nontemporal_store(acc, outb + (size_t)local * CH4);
        }
    }
}

extern "C" void kernel_launch(void* const* d_in, const int* in_sizes, int n_in,
                              void* d_out, int out_size, void* d_ws, size_t ws_size,
                              hipStream_t stream) {
    const float* fm   = (const float*)d_in[0];
    const float* rois = (const float*)d_in[1];
    float* out        = (float*)d_out;
    ROIPoolingLayer_62079457296467_kernel<<<NBLK, 256, 0, stream>>>(fm, rois, out);
}